// Round 5
// baseline (69.622 us; speedup 1.0000x reference)
//
#include <hip/hip_runtime.h>

// Problem geometry (fixed by the reference)
#define HH    2160
#define WW    3840
#define CROPC 3
#define NN    (HH - 2*CROPC)   // 2154 output rows
#define WFLAT (WW * 3)         // 11520 flat columns

constexpr int BAND  = 64;           // output rows per block (4 chunks of 16)
constexpr int CHNK  = 16;           // rows per inner iteration
constexpr int NIT   = BAND / CHNK;  // 4
constexpr int TXF   = 192;          // output flat cols per block; 11520/192 = 60
constexpr int SX    = TXF + 18;     // 210 flat halo cols (12 left, 6 right)
constexpr int NTH   = 256;

// De-interleaved LDS: 3 channel planes of [CHNK rows][PSTR cols] (+8 skew/plane)
constexpr int PSTR  = 76;            // mult of 4 (b128 rows); 76%32=12 spreads banks
constexpr int PLANE = CHNK * PSTR + 8; // 1224 dwords; total 14,688 B

__device__ __forceinline__ float med3f(float a, float b, float c) {
    return fmaxf(fminf(a, b), fminf(fmaxf(a, b), c));
}
// median of 5: 4-element sort network + med3 merge (12 min/max)
__device__ __forceinline__ float med5f(float a, float b, float c, float d, float e) {
    float t;
    t = fminf(a, b); b = fmaxf(a, b); a = t;
    t = fminf(c, d); d = fmaxf(c, d); c = t;
    t = fminf(a, c); c = fmaxf(a, c); a = t;
    t = fminf(b, d); d = fmaxf(b, d); b = t;
    t = fminf(b, c); c = fmaxf(b, c); b = t;
    return fminf(c, fmaxf(b, e));
}

__global__ __launch_bounds__(NTH, 7) void fused_median(const float* __restrict__ img,
                                                       float* __restrict__ out) {
    __shared__ float v2s[3 * PLANE];   // 14,688 B

    const int tid = threadIdx.x;
    const int r0 = blockIdx.y * BAND;
    const int f0 = blockIdx.x * TXF;

    // phase-1 column ownership (1 flat halo col/thread, 210 active)
    const bool p1   = (tid < SX);
    const int  ch   = tid % 3;            // f0 mult of 3 -> channel = tid%3
    const int  pcol = tid / 3;            // plane col <-> img col f0/3-4+pcol
    const int  cc   = min(max(f0 / 3 - 4 + pcol, 0), WW - 1);
    const float* colp = img + (size_t)CROPC * WFLAT + (cc * 3 + ch);

    // phase-2 ownership (16 rows x 16 chunks of 4 img cols)
    const int lr    = tid >> 4;
    const int kk    = tid & 15;
    const int cbase = f0 / 3 + 4 * kk;
    const bool edge2 = (cbase <= 1) || (cbase + 3 >= WW - 1);

    // rolling vertical state: x window x[R-2..R+1], v carries v[R-2],v[R-1]
    float xw0, xw1, xw2, xw3, vm2, vm1;
    float buf[2][CHNK];                   // double-buffered row chunk (static idx only)

    if (p1) {
        // prologue: x[r0-4 .. r0+1] seeds window + carries; chunk0 = x[r0+2 .. r0+17]
        float p[6];
        #pragma unroll
        for (int i = 0; i < 6; ++i) {
            const int rr = min(max(r0 - 4 + i, 0), NN - 1);   // wave-uniform
            p[i] = colp[(size_t)rr * WFLAT];
        }
        #pragma unroll
        for (int i = 0; i < CHNK; ++i) {
            const int rr = min(r0 + 2 + i, NN - 1);
            buf[0][i] = colp[(size_t)rr * WFLAT];
        }
        vm2 = med5f(p[0], p[1], p[2], p[3], p[4]);   // v[r0-2] (edge-clamped = reference)
        vm1 = med5f(p[1], p[2], p[3], p[4], p[5]);   // v[r0-1]
        xw0 = p[2]; xw1 = p[3]; xw2 = p[4]; xw3 = p[5];
    }

    #pragma unroll
    for (int k = 0; k < NIT; ++k) {
        const int Rk = r0 + CHNK * k;

        if (p1) {
            // prefetch next chunk's 16 rows (hidden under this iter's compute)
            if (k < NIT - 1) {
                #pragma unroll
                for (int i = 0; i < CHNK; ++i) {
                    const int rr = min(Rk + CHNK + 2 + i, NN - 1);
                    buf[(k & 1) ^ 1][i] = colp[(size_t)rr * WFLAT];
                }
            }
            // vertical med5 + shift/med3 for rows Rk..Rk+15 (zero redundancy)
            #pragma unroll
            for (int j = 0; j < CHNK; ++j) {
                const float xn = buf[k & 1][j];
                const float vc = med5f(xw0, xw1, xw2, xw3, xn);   // v[Rk+j]
                const int rz = Rk + j;
                // v2[rz] = med3(v[rz-2],v[rz-1],v[rz]); shift1 edge algebra:
                //  rz==0 -> 0 ; rz==1 -> med3(0,v0,v1) ; rz==NN-1 -> v[NN-2]
                float a = vm2, b = vm1;
                if (rz == NN - 1) a = b;
                if (rz == 1)      a = 0.f;
                if (rz == 0)    { a = 0.f; b = 0.f; }
                v2s[ch * PLANE + j * PSTR + pcol] = med3f(a, b, vc);
                xw0 = xw1; xw1 = xw2; xw2 = xw3; xw3 = xn;
                vm2 = vm1; vm1 = vc;
            }
        }
        __syncthreads();

        // phase 2: horizontal med5 + shift/med3 on rows Rk..Rk+15
        const int r_out = Rk + lr;
        if (r_out < NN) {
            float o[12];
            #pragma unroll
            for (int c = 0; c < 3; ++c) {
                // plane cols 4kk..4kk+9 == img cols cbase-4..cbase+5 (clamped)
                const float* pb = &v2s[c * PLANE + lr * PSTR + 4 * kk]; // 16B aligned
                const float4 q0 = *(const float4*)(pb);
                const float4 q1 = *(const float4*)(pb + 4);
                const float2 q2 = *(const float2*)(pb + 8);
                const float ss[10] = {q0.x,q0.y,q0.z,q0.w, q1.x,q1.y,q1.z,q1.w,
                                      q2.x,q2.y};
                float h[6];
                #pragma unroll
                for (int m = 0; m < 6; ++m)
                    h[m] = med5f(ss[m], ss[m+1], ss[m+2], ss[m+3], ss[m+4]);
                if (!edge2) {
                    #pragma unroll
                    for (int n = 0; n < 4; ++n)
                        o[3*n + c] = med3f(h[n], h[n+1], h[n+2]);
                } else {
                    #pragma unroll
                    for (int n = 0; n < 4; ++n) {
                        const int ci = cbase + n;
                        float A = h[n], B = h[n+1];
                        if (ci == WW - 1) A = B;
                        if (ci == 1)      A = 0.f;
                        if (ci == 0)    { A = 0.f; B = 0.f; }
                        o[3*n + c] = med3f(A, B, h[n+2]);
                    }
                }
            }
            float4* op = (float4*)(out + (size_t)r_out * WFLAT + f0 + 12 * kk);
            op[0] = make_float4(o[0], o[1], o[2],  o[3]);
            op[1] = make_float4(o[4], o[5], o[6],  o[7]);
            op[2] = make_float4(o[8], o[9], o[10], o[11]);
        }
        __syncthreads();   // v2s consumed before next iter overwrites
    }
}

extern "C" void kernel_launch(void* const* d_in, const int* in_sizes, int n_in,
                              void* d_out, int out_size, void* d_ws, size_t ws_size,
                              hipStream_t stream) {
    const float* img = (const float*)d_in[0];   // (2160, 3840, 3) fp32
    // d_in[1] = mask (unused by reference), d_in[2] = vertical_size (== 5)
    float* out = (float*)d_out;                 // (2154, 3840, 3) fp32
    dim3 grid(WFLAT / TXF, (NN + BAND - 1) / BAND); // 60 x 34
    fused_median<<<grid, NTH, 0, stream>>>(img, out);
}

// Round 6
// 56.778 us; speedup vs baseline: 1.2262x; 1.2262x over previous
//
#include <hip/hip_runtime.h>

// Problem geometry (fixed by the reference)
#define HH    2160
#define WW    3840
#define CROPC 3
#define NN    (HH - 2*CROPC)   // 2154 output rows
#define WFLAT (WW * 3)         // 11520 flat columns

constexpr int BAND  = 64;            // output rows per block (4 static chunks of 16)
constexpr int CHNK  = 16;
constexpr int NIT   = BAND / CHNK;   // 4
constexpr int TXF   = 192;           // output flat cols per block; 11520/192 = 60
constexpr int SX    = TXF + 18;      // 210 flat halo cols (12 left, 6 right)
constexpr int NTH   = 256;

// De-interleaved LDS: 3 channel planes of [CHNK rows][PSTR cols] (+8 skew/plane)
constexpr int PSTR  = 76;              // mult of 4 (b128 rows); 76%32=12 spreads banks
constexpr int PLANE = CHNK * PSTR + 8; // 1224 dwords; total 14,688 B

__device__ __forceinline__ float med3f(float a, float b, float c) {
    return fmaxf(fminf(a, b), fminf(fmaxf(a, b), c));
}
// median of 5: 4-element sort network + med3 merge (12 min/max)
__device__ __forceinline__ float med5f(float a, float b, float c, float d, float e) {
    float t;
    t = fminf(a, b); b = fmaxf(a, b); a = t;
    t = fminf(c, d); d = fmaxf(c, d); c = t;
    t = fminf(a, c); c = fmaxf(a, c); a = t;
    t = fminf(b, d); d = fmaxf(b, d); b = t;
    t = fminf(b, c); c = fmaxf(b, c); b = t;
    return fminf(c, fmaxf(b, e));
}

// LDS-only barrier: waits DS ops but deliberately leaves global register
// loads (vmcnt) in flight across the barrier — the prefetch pipeline.
__device__ __forceinline__ void lds_barrier() {
    asm volatile("s_waitcnt lgkmcnt(0)\n\ts_barrier" ::: "memory");
}

// One 16-row chunk: phase1 (consume RB) -> barrier -> prefetch (fill WB,
// overlapped with phase2) -> phase2 -> barrier. K, RB, WB are compile-time.
#define DO_CHUNK(K, RB, WB)                                                   \
  {                                                                           \
    const int Rk = r0 + CHNK * (K);                                           \
    if (p1) {                                                                 \
      _Pragma("unroll")                                                       \
      for (int j = 0; j < CHNK; ++j) {                                        \
        const float xn = RB[j];                                               \
        const float vc = med5f(xw0, xw1, xw2, xw3, xn);   /* v[Rk+j] */       \
        const int rz = Rk + j;                                                \
        /* v2[rz]=med3(v[rz-2],v[rz-1],v[rz]); shift1 edge algebra */         \
        float a = vm2, b = vm1;                                               \
        if (rz == NN - 1) a = b;                                              \
        if (rz == 1)      a = 0.f;                                            \
        if (rz == 0)    { a = 0.f; b = 0.f; }                                 \
        v2p[j * PSTR] = med3f(a, b, vc);                                      \
        xw0 = xw1; xw1 = xw2; xw2 = xw3; xw3 = xn;                            \
        vm2 = vm1; vm1 = vc;                                                  \
      }                                                                       \
    }                                                                         \
    lds_barrier();                                                            \
    if ((K) < NIT - 1 && p1) {        /* prefetch next chunk's 16 rows */     \
      _Pragma("unroll")                                                       \
      for (int i = 0; i < CHNK; ++i) {                                        \
        const int rr = min(Rk + CHNK + 2 + i, NN - 1);                        \
        WB[i] = colp[(size_t)rr * WFLAT];                                     \
      }                                                                       \
    }                                                                         \
    {                                  /* phase 2 on rows Rk..Rk+15 */        \
      const int r_out = Rk + lr;                                              \
      if (r_out < NN) {                                                       \
        float o[12];                                                          \
        _Pragma("unroll")                                                     \
        for (int c = 0; c < 3; ++c) {                                         \
          const float* pb = &v2s[c * PLANE + lr * PSTR + 4 * kk];             \
          const float4 q0 = *(const float4*)(pb);                             \
          const float4 q1 = *(const float4*)(pb + 4);                         \
          const float2 q2 = *(const float2*)(pb + 8);                         \
          const float ss[10] = {q0.x,q0.y,q0.z,q0.w, q1.x,q1.y,q1.z,q1.w,     \
                                q2.x,q2.y};                                   \
          float h[6];                                                         \
          _Pragma("unroll")                                                   \
          for (int m = 0; m < 6; ++m)                                         \
            h[m] = med5f(ss[m], ss[m+1], ss[m+2], ss[m+3], ss[m+4]);          \
          if (!edge2) {                                                       \
            _Pragma("unroll")                                                 \
            for (int n = 0; n < 4; ++n)                                       \
              o[3*n + c] = med3f(h[n], h[n+1], h[n+2]);                       \
          } else {                                                            \
            _Pragma("unroll")                                                 \
            for (int n = 0; n < 4; ++n) {                                     \
              const int ci = cbase + n;                                       \
              float A = h[n], B = h[n+1];                                     \
              if (ci == WW - 1) A = B;                                        \
              if (ci == 1)      A = 0.f;                                      \
              if (ci == 0)    { A = 0.f; B = 0.f; }                           \
              o[3*n + c] = med3f(A, B, h[n+2]);                               \
            }                                                                 \
          }                                                                   \
        }                                                                     \
        float4* op = (float4*)(out + (size_t)r_out * WFLAT + f0 + 12 * kk);   \
        op[0] = make_float4(o[0], o[1], o[2],  o[3]);                         \
        op[1] = make_float4(o[4], o[5], o[6],  o[7]);                         \
        op[2] = make_float4(o[8], o[9], o[10], o[11]);                        \
      }                                                                       \
    }                                                                         \
    if ((K) < NIT - 1) lds_barrier();  /* v2s consumed before overwrite */    \
  }

__global__ __launch_bounds__(NTH, 6) void fused_median(const float* __restrict__ img,
                                                       float* __restrict__ out) {
    __shared__ float v2s[3 * PLANE];   // 14,688 B

    const int tid = threadIdx.x;
    const int r0 = blockIdx.y * BAND;
    const int f0 = blockIdx.x * TXF;

    // phase-1 column ownership (1 flat halo col/thread, 210 active)
    const bool p1   = (tid < SX);
    const int  ch   = tid % 3;            // f0 mult of 3 -> channel = tid%3
    const int  pcol = tid / 3;            // plane col <-> img col f0/3-4+pcol
    const int  cc   = min(max(f0 / 3 - 4 + pcol, 0), WW - 1);
    const float* colp = img + (size_t)CROPC * WFLAT + (cc * 3 + ch);
    float* v2p = &v2s[ch * PLANE + pcol];

    // phase-2 ownership (16 rows x 16 chunks of 4 img cols)
    const int lr    = tid >> 4;
    const int kk    = tid & 15;
    const int cbase = f0 / 3 + 4 * kk;
    const bool edge2 = (cbase <= 1) || (cbase + 3 >= WW - 1);

    // rolling vertical state + two statically-named row buffers (never
    // runtime-indexed at the buffer level -> guaranteed registers)
    float xw0 = 0.f, xw1 = 0.f, xw2 = 0.f, xw3 = 0.f, vm2 = 0.f, vm1 = 0.f;
    float bufA[CHNK], bufB[CHNK];

    if (p1) {
        // prologue: 22 batched loads (x[r0-4..r0+1] seeds + chunk0 rows)
        float p[6];
        #pragma unroll
        for (int i = 0; i < 6; ++i) {
            const int rr = min(max(r0 - 4 + i, 0), NN - 1);   // wave-uniform
            p[i] = colp[(size_t)rr * WFLAT];
        }
        #pragma unroll
        for (int i = 0; i < CHNK; ++i) {
            const int rr = min(r0 + 2 + i, NN - 1);
            bufA[i] = colp[(size_t)rr * WFLAT];
        }
        vm2 = med5f(p[0], p[1], p[2], p[3], p[4]);   // v[r0-2]
        vm1 = med5f(p[1], p[2], p[3], p[4], p[5]);   // v[r0-1]
        xw0 = p[2]; xw1 = p[3]; xw2 = p[4]; xw3 = p[5];
    }

    DO_CHUNK(0, bufA, bufB)
    DO_CHUNK(1, bufB, bufA)
    DO_CHUNK(2, bufA, bufB)
    DO_CHUNK(3, bufB, bufA)
}

extern "C" void kernel_launch(void* const* d_in, const int* in_sizes, int n_in,
                              void* d_out, int out_size, void* d_ws, size_t ws_size,
                              hipStream_t stream) {
    const float* img = (const float*)d_in[0];   // (2160, 3840, 3) fp32
    // d_in[1] = mask (unused by reference), d_in[2] = vertical_size (== 5)
    float* out = (float*)d_out;                 // (2154, 3840, 3) fp32
    dim3 grid(WFLAT / TXF, (NN + BAND - 1) / BAND); // 60 x 34
    fused_median<<<grid, NTH, 0, stream>>>(img, out);
}

// Round 7
// 49.856 us; speedup vs baseline: 1.3965x; 1.1388x over previous
//
#include <hip/hip_runtime.h>

// Problem geometry (fixed by the reference)
#define HH    2160
#define WW    3840
#define CROPC 3
#define NN    (HH - 2*CROPC)   // 2154 output rows
#define WFLAT (WW * 3)         // 11520 flat columns

constexpr int TY    = 16;           // output rows per block (small -> high occupancy)
constexpr int TXF   = 192;          // output flat cols per block; 11520/192 = 60
constexpr int SX    = TXF + 18;     // 210 flat halo cols (12 left, 6 right)
constexpr int NTH   = 256;
constexpr int TPR   = 16;           // phase-2 threads per row
constexpr int XROWS = TY + 6;       // 22 input rows per tile

// De-interleaved LDS: 3 channel planes of [TY rows][PSTR cols] (+8 skew per plane).
constexpr int PSTR  = 76;           // mult of 4 (b128-aligned rows); 76%32=12 spreads banks
constexpr int PLANE = TY * PSTR + 8; // 1224 dwords; total 14,688 B -> 8 blocks/CU

__device__ __forceinline__ float med3f(float a, float b, float c) {
    return fmaxf(fminf(a, b), fminf(fmaxf(a, b), c));
}
// median of 5: 4-element sort network + med3 merge (12 min/max)
__device__ __forceinline__ float med5f(float a, float b, float c, float d, float e) {
    float t;
    t = fminf(a, b); b = fmaxf(a, b); a = t;
    t = fminf(c, d); d = fmaxf(c, d); c = t;
    t = fminf(a, c); c = fmaxf(a, c); a = t;
    t = fminf(b, d); d = fmaxf(b, d); b = t;
    t = fminf(b, c); c = fmaxf(b, c); b = t;
    return fminf(c, fmaxf(b, e));
}

__global__ __launch_bounds__(NTH, 8) void fused_median(const float* __restrict__ img,
                                                       float* __restrict__ out) {
    __shared__ float v2s[3 * PLANE];   // 14,688 B

    const int tid = threadIdx.x;
    const int r0 = blockIdx.y * TY;
    const int f0 = blockIdx.x * TXF;

    // ---- Phase 1: vertical med5 + shift/med3, registers only (1 flat col/thread) ----
    if (tid < SX) {
        const int ch   = tid % 3;              // f0 mult of 3 -> channel = tid%3
        const int pcol = tid / 3;              // plane col 0..69 <-> img col f0/3-4+pcol
        const int cc   = min(max(f0 / 3 - 4 + pcol, 0), WW - 1);  // clamped img col
        const float* colp = img + (size_t)CROPC * WFLAT + (cc * 3 + ch);

        // Batch ALL 22 row loads, then PIN the whole batch with one asm that
        // consumes every value: forces all loads issued back-to-back before a
        // single vmcnt drain, and forces all 22 to live in VGPRs (no
        // re-serialization, no scratch). Peak live ~40 VGPR < 64 cap.
        float xv[XROWS];
        #pragma unroll
        for (int i = 0; i < XROWS; ++i) {
            const int rr = min(max(r0 - 4 + i, 0), NN - 1);   // wave-uniform
            xv[i] = colp[(size_t)rr * WFLAT];
        }
        asm volatile("" ::
            "v"(xv[0]),  "v"(xv[1]),  "v"(xv[2]),  "v"(xv[3]),  "v"(xv[4]),
            "v"(xv[5]),  "v"(xv[6]),  "v"(xv[7]),  "v"(xv[8]),  "v"(xv[9]),
            "v"(xv[10]), "v"(xv[11]), "v"(xv[12]), "v"(xv[13]), "v"(xv[14]),
            "v"(xv[15]), "v"(xv[16]), "v"(xv[17]), "v"(xv[18]), "v"(xv[19]),
            "v"(xv[20]), "v"(xv[21]));

        float vm2 = 0.f, vm1 = 0.f;
        #pragma unroll
        for (int i = 4; i < XROWS; ++i) {
            const float vc = med5f(xv[i-4], xv[i-3], xv[i-2], xv[i-1], xv[i]); // v[r0+i-6]
            if (i >= 6) {
                const int rz = r0 + i - 6;
                // v2[rz] = med3(v[rz-2], v[rz-1], v[rz]); shift1 edge algebra:
                //  rz==0 -> 0 ; rz==1 -> med3(0,v0,v1) ; rz==NN-1 -> v[NN-2]
                float a = vm2, b = vm1;
                if (rz == NN - 1) a = b;
                if (rz == 1)      a = 0.f;
                if (rz == 0)    { a = 0.f; b = 0.f; }
                v2s[ch * PLANE + (i - 6) * PSTR + pcol] = med3f(a, b, vc);
            }
            vm2 = vm1; vm1 = vc;
        }
    }
    __syncthreads();

    // ---- Phase 2: horizontal med5 + shift/med3; 16 rows x 16 chunks of 4 img cols ----
    const int lr    = tid >> 4;          // row 0..15
    const int kk    = tid & (TPR - 1);   // chunk 0..15
    const int r_out = r0 + lr;
    if (r_out >= NN) return;             // no barriers after this

    const int cbase = f0 / 3 + 4 * kk;   // first output img col (4 cols/thread)
    const bool edge = (cbase <= 1) || (cbase + 3 >= WW - 1);

    float o[12];
    #pragma unroll
    for (int c = 0; c < 3; ++c) {
        // plane cols 4kk .. 4kk+9 == img cols cbase-4 .. cbase+5 (clamped)
        const float* pb = &v2s[c * PLANE + lr * PSTR + 4 * kk];  // 16B aligned
        const float4 q0 = *(const float4*)(pb);
        const float4 q1 = *(const float4*)(pb + 4);
        const float2 q2 = *(const float2*)(pb + 8);
        const float ss[10] = {q0.x,q0.y,q0.z,q0.w, q1.x,q1.y,q1.z,q1.w,
                              q2.x,q2.y};
        float h[6];
        #pragma unroll
        for (int m = 0; m < 6; ++m)
            h[m] = med5f(ss[m], ss[m+1], ss[m+2], ss[m+3], ss[m+4]); // h1[cbase-2+m]
        if (!edge) {
            #pragma unroll
            for (int n = 0; n < 4; ++n)
                o[3*n + c] = med3f(h[n], h[n+1], h[n+2]);
        } else {
            #pragma unroll
            for (int n = 0; n < 4; ++n) {
                const int ci = cbase + n;
                float A = h[n], B = h[n+1];
                if (ci == WW - 1) A = B;
                if (ci == 1)      A = 0.f;
                if (ci == 0)    { A = 0.f; B = 0.f; }
                o[3*n + c] = med3f(A, B, h[n+2]);
            }
        }
    }

    // 3 aligned float4 stores (f0 + 12kk mult of 4)
    float4* op = (float4*)(out + (size_t)r_out * WFLAT + f0 + 12 * kk);
    op[0] = make_float4(o[0], o[1], o[2],  o[3]);
    op[1] = make_float4(o[4], o[5], o[6],  o[7]);
    op[2] = make_float4(o[8], o[9], o[10], o[11]);
}

extern "C" void kernel_launch(void* const* d_in, const int* in_sizes, int n_in,
                              void* d_out, int out_size, void* d_ws, size_t ws_size,
                              hipStream_t stream) {
    const float* img = (const float*)d_in[0];   // (2160, 3840, 3) fp32
    // d_in[1] = mask (unused by reference), d_in[2] = vertical_size (== 5)
    float* out = (float*)d_out;                 // (2154, 3840, 3) fp32
    dim3 grid(WFLAT / TXF, (NN + TY - 1) / TY); // 60 x 135
    fused_median<<<grid, NTH, 0, stream>>>(img, out);
}